// Round 1
// baseline (4076.196 us; speedup 1.0000x reference)
//
#include <hip/hip_runtime.h>
#include <hip/hip_fp16.h>
#include <math.h>

#define S_ENC 512
#define S_DEC 256
#define HID   1024
#define NCLS  32000
#define KOUT  2048

typedef _Float16 f16;
typedef _Float16 f16x8 __attribute__((ext_vector_type(8)));
typedef _Float16 f16x4 __attribute__((ext_vector_type(4)));
typedef float    f32x4 __attribute__((ext_vector_type(4)));

__device__ __forceinline__ f16x8 cvt8(float4 a, float4 b) {
  f16x8 r;
  r[0] = (f16)a.x; r[1] = (f16)a.y; r[2] = (f16)a.z; r[3] = (f16)a.w;
  r[4] = (f16)b.x; r[5] = (f16)b.y; r[6] = (f16)b.z; r[7] = (f16)b.w;
  return r;
}

// ---------------------------------------------------------------------------
// Split-K NT GEMM: P[z][m][n] = sum_{k in chunk z} A[m,k]*B[n,k]
// Tile 256(M) x 64(N), BK=32, fp32 inputs converted to fp16 in staging,
// MFMA f32_16x16x32_f16. LDS granule-XOR swizzle: granule(row,q) stored at
// row*4 + (q ^ ((row>>1)&3)) -> conflict-free writes and frag reads.
// ---------------------------------------------------------------------------
__global__ __launch_bounds__(256, 2)
void gemm_nt_part(const float* __restrict__ A, const float* __restrict__ B,
                  float* __restrict__ P, int M, int N, int K, int KC)
{
  __shared__ f16x8 As8[256 * 4];
  __shared__ f16x8 Bs8[64 * 4];
  const int tid  = threadIdx.x;
  const int lane = tid & 63;
  const int wv   = tid >> 6;
  const int m0 = blockIdx.x << 8;
  const int n0 = blockIdx.y << 6;
  const int k0 = blockIdx.z * KC;

  f32x4 acc[4][4];
#pragma unroll
  for (int p = 0; p < 4; ++p)
#pragma unroll
    for (int f = 0; f < 4; ++f)
      acc[p][f] = (f32x4){0.f, 0.f, 0.f, 0.f};

  const int swa  = (tid >> 1) & 3;
  const int brow = tid & 63;
  const int bq   = tid >> 6;
  const int swb  = (brow >> 1) & 3;
  const int q    = lane >> 4;
  const int rl   = lane & 15;

  for (int kk = k0; kk < k0 + KC; kk += 32) {
    const float4* sa = (const float4*)(A + (size_t)(m0 + tid) * K + kk);
    float4 av[8];
#pragma unroll
    for (int j = 0; j < 8; ++j) av[j] = sa[j];
    const float4* sb = (const float4*)(B + (size_t)(n0 + brow) * K + kk);
    float4 bv0 = sb[2 * bq];
    float4 bv1 = sb[2 * bq + 1];
#pragma unroll
    for (int g = 0; g < 4; ++g)
      As8[(tid << 2) + (g ^ swa)] = cvt8(av[2 * g], av[2 * g + 1]);
    Bs8[(brow << 2) + (bq ^ swb)] = cvt8(bv0, bv1);
    __syncthreads();

    f16x8 af[4], bf[4];
#pragma unroll
    for (int p = 0; p < 4; ++p) {
      int r = (wv << 6) + (p << 4) + rl;
      af[p] = As8[(r << 2) + (q ^ ((r >> 1) & 3))];
    }
#pragma unroll
    for (int f = 0; f < 4; ++f) {
      int c = (f << 4) + rl;
      bf[f] = Bs8[(c << 2) + (q ^ ((c >> 1) & 3))];
    }
#pragma unroll
    for (int p = 0; p < 4; ++p)
#pragma unroll
      for (int f = 0; f < 4; ++f)
        acc[p][f] = __builtin_amdgcn_mfma_f32_16x16x32_f16(af[p], bf[f], acc[p][f], 0, 0, 0);
    __syncthreads();
  }

  float* Pz = P + (size_t)blockIdx.z * M * N;
#pragma unroll
  for (int p = 0; p < 4; ++p)
#pragma unroll
    for (int i = 0; i < 4; ++i) {
      int row = m0 + (wv << 6) + (p << 4) + (q << 2) + i;
      float* dst = Pz + (size_t)row * N + n0 + rl;
#pragma unroll
      for (int f = 0; f < 4; ++f)
        dst[f << 4] = acc[p][f][i];
    }
}

// ---------------------------------------------------------------------------
// Output GEMM: C[256,32000] = HC16[256,2048](f16) * out_W[32000,2048]^T + b
// Tile 256 x 64, no split-K (K=2048, 500 blocks).
// ---------------------------------------------------------------------------
__global__ __launch_bounds__(256, 2)
void gemm_out_f16(const f16* __restrict__ A16, const float* __restrict__ B,
                  const float* __restrict__ bias, float* __restrict__ C)
{
  __shared__ f16x8 As8[256 * 4];
  __shared__ f16x8 Bs8[64 * 4];
  const int tid  = threadIdx.x;
  const int lane = tid & 63;
  const int wv   = tid >> 6;
  const int n0   = blockIdx.x << 6;

  f32x4 acc[4][4];
#pragma unroll
  for (int p = 0; p < 4; ++p)
#pragma unroll
    for (int f = 0; f < 4; ++f)
      acc[p][f] = (f32x4){0.f, 0.f, 0.f, 0.f};

  const int swa  = (tid >> 1) & 3;
  const int brow = tid & 63;
  const int bq   = tid >> 6;
  const int swb  = (brow >> 1) & 3;
  const int q    = lane >> 4;
  const int rl   = lane & 15;

  for (int kk = 0; kk < KOUT; kk += 32) {
    const uint4* sa = (const uint4*)(A16 + (size_t)tid * KOUT + kk);
    uint4 av[4];
#pragma unroll
    for (int g = 0; g < 4; ++g) av[g] = sa[g];
    const float4* sb = (const float4*)(B + (size_t)(n0 + brow) * KOUT + kk);
    float4 bv0 = sb[2 * bq];
    float4 bv1 = sb[2 * bq + 1];
#pragma unroll
    for (int g = 0; g < 4; ++g)
      ((uint4*)As8)[(tid << 2) + (g ^ swa)] = av[g];
    Bs8[(brow << 2) + (bq ^ swb)] = cvt8(bv0, bv1);
    __syncthreads();

    f16x8 af[4], bf[4];
#pragma unroll
    for (int p = 0; p < 4; ++p) {
      int r = (wv << 6) + (p << 4) + rl;
      af[p] = As8[(r << 2) + (q ^ ((r >> 1) & 3))];
    }
#pragma unroll
    for (int f = 0; f < 4; ++f) {
      int c = (f << 4) + rl;
      bf[f] = Bs8[(c << 2) + (q ^ ((c >> 1) & 3))];
    }
#pragma unroll
    for (int p = 0; p < 4; ++p)
#pragma unroll
      for (int f = 0; f < 4; ++f)
        acc[p][f] = __builtin_amdgcn_mfma_f32_16x16x32_f16(af[p], bf[f], acc[p][f], 0, 0, 0);
    __syncthreads();
  }

  float bv[4];
#pragma unroll
  for (int f = 0; f < 4; ++f) bv[f] = bias[n0 + (f << 4) + rl];
#pragma unroll
  for (int p = 0; p < 4; ++p)
#pragma unroll
    for (int i = 0; i < 4; ++i) {
      int row = (wv << 6) + (p << 4) + (q << 2) + i;
      float* dst = C + (size_t)row * NCLS + n0 + rl;
#pragma unroll
      for (int f = 0; f < 4; ++f)
        dst[f << 4] = acc[p][f][i] + bv[f];
    }
}

// ---------------------------------------------------------------------------
// reduce split-K partials + bias (N is always 1024 here)
// ---------------------------------------------------------------------------
__global__ void reduce_bias(const float* __restrict__ P, const float* __restrict__ bias,
                            float* __restrict__ out, int MN, int Z)
{
  int idx = blockIdx.x * 256 + threadIdx.x;
  if (idx >= MN) return;
  float s = bias[idx & (HID - 1)];
  for (int z = 0; z < Z; ++z) s += P[(size_t)z * MN + idx];
  out[idx] = s;
}

__global__ void init_flags(int* __restrict__ f) { f[threadIdx.x] = 0; }

// ---------------------------------------------------------------------------
// Sequential RNN scan: h_{t+1} = tanh(xw[t] + Whh h_t + bhh)
// 64 WGs x 256 thr. WG owns 16 rows; wave owns 4 rows; lane holds the
// k-slice [lane*16, lane*16+16) of each of its 4 rows in VGPRs (64 regs).
// h in LDS (XOR-swizzled granules), double-buffered in global for the
// cross-WG exchange. Per-step sync: per-WG release flag + 64-lane poll.
// ---------------------------------------------------------------------------
__device__ __forceinline__ int hcpos(int g) { return (g ^ ((g >> 3) & 7)) << 2; }

__global__ __launch_bounds__(256)
void rnn_scan(const float* __restrict__ Whh, const float* __restrict__ bhh,
              const float* __restrict__ xw, const float* __restrict__ h0,
              float* __restrict__ Eout, f16* __restrict__ H16,
              float* __restrict__ hbuf, int* __restrict__ flags, int T)
{
  __shared__ float hc[HID];
  const int tid  = threadIdx.x;
  const int lane = tid & 63;
  const int wv   = tid >> 6;
  const int wid  = blockIdx.x;
  const int rbase = (wid << 4) + (wv << 2);

  float4 W[4][4];
#pragma unroll
  for (int rr = 0; rr < 4; ++rr)
#pragma unroll
    for (int g = 0; g < 4; ++g)
      W[rr][g] = *(const float4*)(Whh + (size_t)(rbase + rr) * HID + (lane << 4) + (g << 2));

  const int myrow = rbase + lane;          // valid when lane < 4
  float mybias = (lane < 4) ? bhh[myrow] : 0.f;

  *(float4*)(hc + hcpos(tid)) = *(const float4*)(h0 + (tid << 2));
  __syncthreads();

  for (int t = 0; t < T; ++t) {
    float4 hv[4];
#pragma unroll
    for (int g = 0; g < 4; ++g)
      hv[g] = *(const float4*)(hc + hcpos((lane << 2) + g));
    float p[4];
#pragma unroll
    for (int rr = 0; rr < 4; ++rr) {
      float s = 0.f;
#pragma unroll
      for (int g = 0; g < 4; ++g) {
        s = fmaf(W[rr][g].x, hv[g].x, s);
        s = fmaf(W[rr][g].y, hv[g].y, s);
        s = fmaf(W[rr][g].z, hv[g].z, s);
        s = fmaf(W[rr][g].w, hv[g].w, s);
      }
      p[rr] = s;
    }
#pragma unroll
    for (int d = 32; d >= 1; d >>= 1) {
#pragma unroll
      for (int rr = 0; rr < 4; ++rr)
        p[rr] += __shfl_xor(p[rr], d);
    }
    if (lane < 4) {
      float z = p[lane] + xw[(size_t)t * HID + myrow] + mybias;
      float h = tanhf(z);
      __hip_atomic_store(hbuf + (((t + 1) & 1) << 10) + myrow, h,
                         __ATOMIC_RELAXED, __HIP_MEMORY_SCOPE_AGENT);
      if (Eout) Eout[(size_t)t * HID + myrow] = h;
      if (H16)  H16[(size_t)t * KOUT + myrow] = (f16)h;
    }
    __syncthreads();   // drains vmcnt for every wave before the flag
    if (tid == 0)
      __hip_atomic_store(&flags[wid << 2], t + 1, __ATOMIC_RELEASE, __HIP_MEMORY_SCOPE_AGENT);
    if (wv == 0) {
      while (__hip_atomic_load(&flags[lane << 2], __ATOMIC_ACQUIRE,
                               __HIP_MEMORY_SCOPE_AGENT) <= t) {}
    }
    __syncthreads();
    *(float4*)(hc + hcpos(tid)) =
        *(const float4*)(hbuf + (((t + 1) & 1) << 10) + (tid << 2));
    __syncthreads();
  }
}

// ---------------------------------------------------------------------------
// scores + softmax: per decoder step t: s = Abuf . h_t ; w = softmax(s)
// ---------------------------------------------------------------------------
__global__ __launch_bounds__(256, 4)
void attn_scores(const f16* __restrict__ HC16, const float* __restrict__ Abuf,
                 float* __restrict__ attns, float* __restrict__ wbuf)
{
  __shared__ float h[HID];
  __shared__ float red[8];
  const int t = blockIdx.x;
  const int tid = threadIdx.x;
  const int lane = tid & 63;
  const int wv = tid >> 6;
  {
    f16x4 v = *(const f16x4*)(HC16 + (size_t)t * KOUT + (tid << 2));
    float4 f;
    f.x = (float)v[0]; f.y = (float)v[1]; f.z = (float)v[2]; f.w = (float)v[3];
    *(float4*)(h + (tid << 2)) = f;
  }
  __syncthreads();
  float s0 = 0.f, s1 = 0.f;
  {
    const float4* A0 = (const float4*)(Abuf + (size_t)tid * HID);
    const float4* A1 = (const float4*)(Abuf + (size_t)(tid + 256) * HID);
    float a0x = 0, a0y = 0, a0z = 0, a0w = 0, a1x = 0, a1y = 0, a1z = 0, a1w = 0;
#pragma unroll 8
    for (int j = 0; j < 256; ++j) {
      float4 hv = *(const float4*)(h + (j << 2));
      float4 a0 = A0[j];
      float4 a1 = A1[j];
      a0x = fmaf(a0.x, hv.x, a0x); a0y = fmaf(a0.y, hv.y, a0y);
      a0z = fmaf(a0.z, hv.z, a0z); a0w = fmaf(a0.w, hv.w, a0w);
      a1x = fmaf(a1.x, hv.x, a1x); a1y = fmaf(a1.y, hv.y, a1y);
      a1z = fmaf(a1.z, hv.z, a1z); a1w = fmaf(a1.w, hv.w, a1w);
    }
    s0 = (a0x + a0y) + (a0z + a0w);
    s1 = (a1x + a1y) + (a1z + a1w);
  }
  float m = fmaxf(s0, s1);
#pragma unroll
  for (int d = 32; d >= 1; d >>= 1) m = fmaxf(m, __shfl_xor(m, d));
  if (lane == 0) red[wv] = m;
  __syncthreads();
  float M = fmaxf(fmaxf(red[0], red[1]), fmaxf(red[2], red[3]));
  float e0 = expf(s0 - M);
  float e1 = expf(s1 - M);
  float ss = e0 + e1;
#pragma unroll
  for (int d = 32; d >= 1; d >>= 1) ss += __shfl_xor(ss, d);
  if (lane == 0) red[4 + wv] = ss;
  __syncthreads();
  float inv = 1.f / (red[4] + red[5] + red[6] + red[7]);
  float w0 = e0 * inv, w1 = e1 * inv;
  attns[(size_t)t * S_ENC + tid]       = w0;
  attns[(size_t)t * S_ENC + 256 + tid] = w1;
  wbuf[(size_t)t * S_ENC + tid]        = w0;
  wbuf[(size_t)t * S_ENC + 256 + tid]  = w1;
}

// ---------------------------------------------------------------------------
// context: HC16[t, 1024+j] = sum_i w[t,i] * E[i,j]
// ---------------------------------------------------------------------------
__global__ __launch_bounds__(256, 4)
void attn_context(const float* __restrict__ wbuf, const float* __restrict__ E,
                  f16* __restrict__ HC16)
{
  __shared__ float w[S_ENC];
  const int t = blockIdx.x;
  const int tid = threadIdx.x;
  w[tid]       = wbuf[(size_t)t * S_ENC + tid];
  w[tid + 256] = wbuf[(size_t)t * S_ENC + 256 + tid];
  __syncthreads();
  float ax = 0, ay = 0, az = 0, aw = 0;
  const float4* Eb = (const float4*)E + tid;
#pragma unroll 4
  for (int i = 0; i < S_ENC; ++i) {
    float wi = w[i];
    float4 e = Eb[(size_t)i * 256];
    ax = fmaf(wi, e.x, ax); ay = fmaf(wi, e.y, ay);
    az = fmaf(wi, e.z, az); aw = fmaf(wi, e.w, aw);
  }
  f16x4 o;
  o[0] = (f16)ax; o[1] = (f16)ay; o[2] = (f16)az; o[3] = (f16)aw;
  *(f16x4*)(HC16 + (size_t)t * KOUT + HID + (tid << 2)) = o;
}

// ---------------------------------------------------------------------------
extern "C" void kernel_launch(void* const* d_in, const int* in_sizes, int n_in,
                              void* d_out, int out_size, void* d_ws, size_t ws_size,
                              hipStream_t stream)
{
  const float* enc_input = (const float*)d_in[0];
  const float* hidden    = (const float*)d_in[1];
  const float* dec_input = (const float*)d_in[2];
  const float* enc_W_ih  = (const float*)d_in[3];
  const float* enc_W_hh  = (const float*)d_in[4];
  const float* enc_b_ih  = (const float*)d_in[5];
  const float* enc_b_hh  = (const float*)d_in[6];
  const float* dec_W_ih  = (const float*)d_in[7];
  const float* dec_W_hh  = (const float*)d_in[8];
  const float* dec_b_ih  = (const float*)d_in[9];
  const float* dec_b_hh  = (const float*)d_in[10];
  const float* attn_W    = (const float*)d_in[11];
  const float* attn_b    = (const float*)d_in[12];
  const float* out_W     = (const float*)d_in[13];
  const float* out_b     = (const float*)d_in[14];

  float* outs  = (float*)d_out;                         // [256, 32000]
  float* attns = (float*)d_out + (size_t)S_DEC * NCLS;  // [256, 512]

  // workspace layout (float units); total ~34.1 MB
  float* wsf     = (float*)d_ws;
  float* xw_enc  = wsf + 0;                  // 524288
  float* xw_dec  = wsf + 524288;             // 262144
  float* Abuf    = wsf + 786432;             // 524288
  float* E       = wsf + 1310720;            // 524288
  float* wbuf    = wsf + 1835008;            // 131072
  float* hbuf_e  = wsf + 1966080;            // 2048
  float* hbuf_d  = wsf + 1968128;            // 2048
  int*   flags   = (int*)(wsf + 1970176);    // 1024 ints (enc: 0..255, dec: 256..511)
  f16*   HC16    = (f16*)(wsf + 1971200);    // 524288 halves
  float* P_enc   = wsf + 2233344;            // 8 * 524288 (also reused as P_A)
  float* P_dec   = wsf + 6427648;            // 8 * 262144
  float* P_A     = P_enc;                    // alias: P_enc dead after its reduce

  init_flags<<<1, 1024, 0, stream>>>(flags);

  gemm_nt_part<<<dim3(2, 16, 8), 256, 0, stream>>>(enc_input, enc_W_ih, P_enc,
                                                   S_ENC, HID, NCLS, 4000);
  gemm_nt_part<<<dim3(1, 16, 8), 256, 0, stream>>>(dec_input, dec_W_ih, P_dec,
                                                   S_DEC, HID, NCLS, 4000);
  reduce_bias<<<2048, 256, 0, stream>>>(P_enc, enc_b_ih, xw_enc, S_ENC * HID, 8);
  reduce_bias<<<1024, 256, 0, stream>>>(P_dec, dec_b_ih, xw_dec, S_DEC * HID, 8);

  rnn_scan<<<64, 256, 0, stream>>>(enc_W_hh, enc_b_hh, xw_enc, hidden,
                                   E, (f16*)nullptr, hbuf_e, flags, S_ENC);

  gemm_nt_part<<<dim3(2, 16, 4), 256, 0, stream>>>(E, attn_W, P_A,
                                                   S_ENC, HID, HID, 256);
  reduce_bias<<<2048, 256, 0, stream>>>(P_A, attn_b, Abuf, S_ENC * HID, 4);

  rnn_scan<<<64, 256, 0, stream>>>(dec_W_hh, dec_b_hh, xw_dec, E + 511 * HID,
                                   (float*)nullptr, HC16, hbuf_d, flags + 256, S_DEC);

  attn_scores<<<256, 256, 0, stream>>>(HC16, Abuf, attns, wbuf);
  attn_context<<<256, 256, 0, stream>>>(wbuf, E, HC16);
  gemm_out_f16<<<500, 256, 0, stream>>>(HC16, out_W, out_b, outs);

  (void)in_sizes; (void)n_in; (void)out_size; (void)ws_size;
}

// Round 2
// 3549.152 us; speedup vs baseline: 1.1485x; 1.1485x over previous
//
#include <hip/hip_runtime.h>
#include <hip/hip_fp16.h>
#include <math.h>

#define S_ENC 512
#define S_DEC 256
#define HID   1024
#define NCLS  32000
#define KOUT  2048

typedef _Float16 f16;
typedef _Float16 f16x8 __attribute__((ext_vector_type(8)));
typedef _Float16 f16x4 __attribute__((ext_vector_type(4)));
typedef float    f32x4 __attribute__((ext_vector_type(4)));

__device__ __forceinline__ f16x8 cvt8(float4 a, float4 b) {
  f16x8 r;
  r[0] = (f16)a.x; r[1] = (f16)a.y; r[2] = (f16)a.z; r[3] = (f16)a.w;
  r[4] = (f16)b.x; r[5] = (f16)b.y; r[6] = (f16)b.z; r[7] = (f16)b.w;
  return r;
}

// ---------------------------------------------------------------------------
// Split-K NT GEMM: P[z][m][n] = sum_{k in chunk z} A[m,k]*B[n,k]
// Tile 256(M) x 64(N), BK=32, fp32 inputs converted to fp16 in staging,
// MFMA f32_16x16x32_f16. LDS granule-XOR swizzle.
// ---------------------------------------------------------------------------
__global__ __launch_bounds__(256, 2)
void gemm_nt_part(const float* __restrict__ A, const float* __restrict__ B,
                  float* __restrict__ P, int M, int N, int K, int KC)
{
  __shared__ f16x8 As8[256 * 4];
  __shared__ f16x8 Bs8[64 * 4];
  const int tid  = threadIdx.x;
  const int lane = tid & 63;
  const int wv   = tid >> 6;
  const int m0 = blockIdx.x << 8;
  const int n0 = blockIdx.y << 6;
  const int k0 = blockIdx.z * KC;

  f32x4 acc[4][4];
#pragma unroll
  for (int p = 0; p < 4; ++p)
#pragma unroll
    for (int f = 0; f < 4; ++f)
      acc[p][f] = (f32x4){0.f, 0.f, 0.f, 0.f};

  const int swa  = (tid >> 1) & 3;
  const int brow = tid & 63;
  const int bq   = tid >> 6;
  const int swb  = (brow >> 1) & 3;
  const int q    = lane >> 4;
  const int rl   = lane & 15;

  for (int kk = k0; kk < k0 + KC; kk += 32) {
    const float4* sa = (const float4*)(A + (size_t)(m0 + tid) * K + kk);
    float4 av[8];
#pragma unroll
    for (int j = 0; j < 8; ++j) av[j] = sa[j];
    const float4* sb = (const float4*)(B + (size_t)(n0 + brow) * K + kk);
    float4 bv0 = sb[2 * bq];
    float4 bv1 = sb[2 * bq + 1];
#pragma unroll
    for (int g = 0; g < 4; ++g)
      As8[(tid << 2) + (g ^ swa)] = cvt8(av[2 * g], av[2 * g + 1]);
    Bs8[(brow << 2) + (bq ^ swb)] = cvt8(bv0, bv1);
    __syncthreads();

    f16x8 af[4], bf[4];
#pragma unroll
    for (int p = 0; p < 4; ++p) {
      int r = (wv << 6) + (p << 4) + rl;
      af[p] = As8[(r << 2) + (q ^ ((r >> 1) & 3))];
    }
#pragma unroll
    for (int f = 0; f < 4; ++f) {
      int c = (f << 4) + rl;
      bf[f] = Bs8[(c << 2) + (q ^ ((c >> 1) & 3))];
    }
#pragma unroll
    for (int p = 0; p < 4; ++p)
#pragma unroll
      for (int f = 0; f < 4; ++f)
        acc[p][f] = __builtin_amdgcn_mfma_f32_16x16x32_f16(af[p], bf[f], acc[p][f], 0, 0, 0);
    __syncthreads();
  }

  float* Pz = P + (size_t)blockIdx.z * M * N;
#pragma unroll
  for (int p = 0; p < 4; ++p)
#pragma unroll
    for (int i = 0; i < 4; ++i) {
      int row = m0 + (wv << 6) + (p << 4) + (q << 2) + i;
      float* dst = Pz + (size_t)row * N + n0 + rl;
#pragma unroll
      for (int f = 0; f < 4; ++f)
        dst[f << 4] = acc[p][f][i];
    }
}

// ---------------------------------------------------------------------------
// Output GEMM: C[256,32000] = HC16[256,2048](f16) * out_W[32000,2048]^T + b
// ---------------------------------------------------------------------------
__global__ __launch_bounds__(256, 2)
void gemm_out_f16(const f16* __restrict__ A16, const float* __restrict__ B,
                  const float* __restrict__ bias, float* __restrict__ C)
{
  __shared__ f16x8 As8[256 * 4];
  __shared__ f16x8 Bs8[64 * 4];
  const int tid  = threadIdx.x;
  const int lane = tid & 63;
  const int wv   = tid >> 6;
  const int n0   = blockIdx.x << 6;

  f32x4 acc[4][4];
#pragma unroll
  for (int p = 0; p < 4; ++p)
#pragma unroll
    for (int f = 0; f < 4; ++f)
      acc[p][f] = (f32x4){0.f, 0.f, 0.f, 0.f};

  const int swa  = (tid >> 1) & 3;
  const int brow = tid & 63;
  const int bq   = tid >> 6;
  const int swb  = (brow >> 1) & 3;
  const int q    = lane >> 4;
  const int rl   = lane & 15;

  for (int kk = 0; kk < KOUT; kk += 32) {
    const uint4* sa = (const uint4*)(A16 + (size_t)tid * KOUT + kk);
    uint4 av[4];
#pragma unroll
    for (int g = 0; g < 4; ++g) av[g] = sa[g];
    const float4* sb = (const float4*)(B + (size_t)(n0 + brow) * KOUT + kk);
    float4 bv0 = sb[2 * bq];
    float4 bv1 = sb[2 * bq + 1];
#pragma unroll
    for (int g = 0; g < 4; ++g)
      ((uint4*)As8)[(tid << 2) + (g ^ swa)] = av[g];
    Bs8[(brow << 2) + (bq ^ swb)] = cvt8(bv0, bv1);
    __syncthreads();

    f16x8 af[4], bf[4];
#pragma unroll
    for (int p = 0; p < 4; ++p) {
      int r = (wv << 6) + (p << 4) + rl;
      af[p] = As8[(r << 2) + (q ^ ((r >> 1) & 3))];
    }
#pragma unroll
    for (int f = 0; f < 4; ++f) {
      int c = (f << 4) + rl;
      bf[f] = Bs8[(c << 2) + (q ^ ((c >> 1) & 3))];
    }
#pragma unroll
    for (int p = 0; p < 4; ++p)
#pragma unroll
      for (int f = 0; f < 4; ++f)
        acc[p][f] = __builtin_amdgcn_mfma_f32_16x16x32_f16(af[p], bf[f], acc[p][f], 0, 0, 0);
    __syncthreads();
  }

  float bv[4];
#pragma unroll
  for (int f = 0; f < 4; ++f) bv[f] = bias[n0 + (f << 4) + rl];
#pragma unroll
  for (int p = 0; p < 4; ++p)
#pragma unroll
    for (int i = 0; i < 4; ++i) {
      int row = (wv << 6) + (p << 4) + (q << 2) + i;
      float* dst = C + (size_t)row * NCLS + n0 + rl;
#pragma unroll
      for (int f = 0; f < 4; ++f)
        dst[f << 4] = acc[p][f][i] + bv[f];
    }
}

// ---------------------------------------------------------------------------
__global__ void reduce_bias(const float* __restrict__ P, const float* __restrict__ bias,
                            float* __restrict__ out, int MN, int Z)
{
  int idx = blockIdx.x * 256 + threadIdx.x;
  if (idx >= MN) return;
  float s = bias[idx & (HID - 1)];
  for (int z = 0; z < Z; ++z) s += P[(size_t)z * MN + idx];
  out[idx] = s;
}

// zero the tagged-h exchange buffers (tag 0 never matches t+1 >= 1)
__global__ void init_hx(unsigned int* __restrict__ hx) {
  ((uint4*)hx)[threadIdx.x] = (uint4){0u, 0u, 0u, 0u};
}

// ---------------------------------------------------------------------------
// Sequential RNN scan: h_{t+1} = tanh(xw[t] + Whh h_t + bhh)
// 64 WGs x 256 thr; W_hh in VGPRs (64/thread). Cross-WG exchange via
// TAGGED words: hx[parity][i] = (t+1)<<16 | f16_bits(h_i). RELAXED atomics
// at AGENT scope (plain sc0/sc1 dword ops, NO L2 writeback/invalidate --
// the release/acquire protocol of round 1 flushed the XCD L2 every step).
// Tag+payload share one word => no fences needed. One barrier per step.
// ---------------------------------------------------------------------------
__device__ __forceinline__ int hcpos(int g) { return (g ^ ((g >> 3) & 7)) << 2; }

__global__ __launch_bounds__(256)
void rnn_scan(const float* __restrict__ Whh, const float* __restrict__ bhh,
              const float* __restrict__ xw, const float* __restrict__ h0,
              float* __restrict__ Eout, f16* __restrict__ H16,
              unsigned int* __restrict__ hx, int T)
{
  __shared__ float hc[HID];
  const int tid  = threadIdx.x;
  const int lane = tid & 63;
  const int wv   = tid >> 6;
  const int wid  = blockIdx.x;
  const int rbase = (wid << 4) + (wv << 2);

  float4 W[4][4];
#pragma unroll
  for (int rr = 0; rr < 4; ++rr)
#pragma unroll
    for (int g = 0; g < 4; ++g)
      W[rr][g] = *(const float4*)(Whh + (size_t)(rbase + rr) * HID + (lane << 4) + (g << 2));

  const int myrow = rbase + lane;          // valid when lane < 4
  float mybias = (lane < 4) ? bhh[myrow] : 0.f;

  *(float4*)(hc + hcpos(tid)) = *(const float4*)(h0 + (tid << 2));
  __syncthreads();

  for (int t = 0; t < T; ++t) {
    // prefetch the input projection early (used after the reduce)
    float xwv = (lane < 4) ? xw[(size_t)t * HID + myrow] : 0.f;

    float4 hv[4];
#pragma unroll
    for (int g = 0; g < 4; ++g)
      hv[g] = *(const float4*)(hc + hcpos((lane << 2) + g));
    float p[4];
#pragma unroll
    for (int rr = 0; rr < 4; ++rr) {
      float s = 0.f;
#pragma unroll
      for (int g = 0; g < 4; ++g) {
        s = fmaf(W[rr][g].x, hv[g].x, s);
        s = fmaf(W[rr][g].y, hv[g].y, s);
        s = fmaf(W[rr][g].z, hv[g].z, s);
        s = fmaf(W[rr][g].w, hv[g].w, s);
      }
      p[rr] = s;
    }
#pragma unroll
    for (int d = 32; d >= 1; d >>= 1) {
#pragma unroll
      for (int rr = 0; rr < 4; ++rr)
        p[rr] += __shfl_xor(p[rr], d);
    }

    const unsigned int tag = (unsigned int)(t + 1);
    const int par = (t + 1) & 1;

    if (lane < 4) {
      float z = p[lane] + xwv + mybias;
      float h = tanhf(z);
      if (Eout) Eout[(size_t)t * HID + myrow] = h;
      f16 h16 = (f16)h;
      if (H16)  H16[(size_t)t * KOUT + myrow] = h16;
      unsigned int wword = (tag << 16) | (unsigned int)__builtin_bit_cast(unsigned short, h16);
      __hip_atomic_store(hx + (par << 10) + myrow, wword,
                         __ATOMIC_RELAXED, __HIP_MEMORY_SCOPE_AGENT);
    }

    if (t + 1 < T) {
      unsigned int* bp = hx + (par << 10) + (tid << 2);
      unsigned int a0, a1, a2, a3;
      do {
        a0 = __hip_atomic_load(bp + 0, __ATOMIC_RELAXED, __HIP_MEMORY_SCOPE_AGENT);
        a1 = __hip_atomic_load(bp + 1, __ATOMIC_RELAXED, __HIP_MEMORY_SCOPE_AGENT);
        a2 = __hip_atomic_load(bp + 2, __ATOMIC_RELAXED, __HIP_MEMORY_SCOPE_AGENT);
        a3 = __hip_atomic_load(bp + 3, __ATOMIC_RELAXED, __HIP_MEMORY_SCOPE_AGENT);
      } while (((a0 >> 16) != tag) | ((a1 >> 16) != tag) |
               ((a2 >> 16) != tag) | ((a3 >> 16) != tag));
      float4 f;
      f.x = (float)__builtin_bit_cast(f16, (unsigned short)(a0 & 0xFFFFu));
      f.y = (float)__builtin_bit_cast(f16, (unsigned short)(a1 & 0xFFFFu));
      f.z = (float)__builtin_bit_cast(f16, (unsigned short)(a2 & 0xFFFFu));
      f.w = (float)__builtin_bit_cast(f16, (unsigned short)(a3 & 0xFFFFu));
      // poll success proves every wave in every WG passed its reduce for
      // step t (its producer store follows the wave-synchronous shuffles),
      // so hc is no longer being read -- safe to overwrite without barrier.
      *(float4*)(hc + hcpos(tid)) = f;
      __syncthreads();   // publish new hc to the other waves of this WG
    }
  }
}

// ---------------------------------------------------------------------------
// scores + softmax: per decoder step t: s = Abuf . h_t ; w = softmax(s)
// ---------------------------------------------------------------------------
__global__ __launch_bounds__(256, 4)
void attn_scores(const f16* __restrict__ HC16, const float* __restrict__ Abuf,
                 float* __restrict__ attns, float* __restrict__ wbuf)
{
  __shared__ float h[HID];
  __shared__ float red[8];
  const int t = blockIdx.x;
  const int tid = threadIdx.x;
  const int lane = tid & 63;
  const int wv = tid >> 6;
  {
    f16x4 v = *(const f16x4*)(HC16 + (size_t)t * KOUT + (tid << 2));
    float4 f;
    f.x = (float)v[0]; f.y = (float)v[1]; f.z = (float)v[2]; f.w = (float)v[3];
    *(float4*)(h + (tid << 2)) = f;
  }
  __syncthreads();
  float s0 = 0.f, s1 = 0.f;
  {
    const float4* A0 = (const float4*)(Abuf + (size_t)tid * HID);
    const float4* A1 = (const float4*)(Abuf + (size_t)(tid + 256) * HID);
    float a0x = 0, a0y = 0, a0z = 0, a0w = 0, a1x = 0, a1y = 0, a1z = 0, a1w = 0;
#pragma unroll 8
    for (int j = 0; j < 256; ++j) {
      float4 hv = *(const float4*)(h + (j << 2));
      float4 a0 = A0[j];
      float4 a1 = A1[j];
      a0x = fmaf(a0.x, hv.x, a0x); a0y = fmaf(a0.y, hv.y, a0y);
      a0z = fmaf(a0.z, hv.z, a0z); a0w = fmaf(a0.w, hv.w, a0w);
      a1x = fmaf(a1.x, hv.x, a1x); a1y = fmaf(a1.y, hv.y, a1y);
      a1z = fmaf(a1.z, hv.z, a1z); a1w = fmaf(a1.w, hv.w, a1w);
    }
    s0 = (a0x + a0y) + (a0z + a0w);
    s1 = (a1x + a1y) + (a1z + a1w);
  }
  float m = fmaxf(s0, s1);
#pragma unroll
  for (int d = 32; d >= 1; d >>= 1) m = fmaxf(m, __shfl_xor(m, d));
  if (lane == 0) red[wv] = m;
  __syncthreads();
  float M = fmaxf(fmaxf(red[0], red[1]), fmaxf(red[2], red[3]));
  float e0 = expf(s0 - M);
  float e1 = expf(s1 - M);
  float ss = e0 + e1;
#pragma unroll
  for (int d = 32; d >= 1; d >>= 1) ss += __shfl_xor(ss, d);
  if (lane == 0) red[4 + wv] = ss;
  __syncthreads();
  float inv = 1.f / (red[4] + red[5] + red[6] + red[7]);
  float w0 = e0 * inv, w1 = e1 * inv;
  attns[(size_t)t * S_ENC + tid]       = w0;
  attns[(size_t)t * S_ENC + 256 + tid] = w1;
  wbuf[(size_t)t * S_ENC + tid]        = w0;
  wbuf[(size_t)t * S_ENC + 256 + tid]  = w1;
}

// ---------------------------------------------------------------------------
// context: HC16[t, 1024+j] = sum_i w[t,i] * E[i,j]
// ---------------------------------------------------------------------------
__global__ __launch_bounds__(256, 4)
void attn_context(const float* __restrict__ wbuf, const float* __restrict__ E,
                  f16* __restrict__ HC16)
{
  __shared__ float w[S_ENC];
  const int t = blockIdx.x;
  const int tid = threadIdx.x;
  w[tid]       = wbuf[(size_t)t * S_ENC + tid];
  w[tid + 256] = wbuf[(size_t)t * S_ENC + 256 + tid];
  __syncthreads();
  float ax = 0, ay = 0, az = 0, aw = 0;
  const float4* Eb = (const float4*)E + tid;
#pragma unroll 4
  for (int i = 0; i < S_ENC; ++i) {
    float wi = w[i];
    float4 e = Eb[(size_t)i * 256];
    ax = fmaf(wi, e.x, ax); ay = fmaf(wi, e.y, ay);
    az = fmaf(wi, e.z, az); aw = fmaf(wi, e.w, aw);
  }
  f16x4 o;
  o[0] = (f16)ax; o[1] = (f16)ay; o[2] = (f16)az; o[3] = (f16)aw;
  *(f16x4*)(HC16 + (size_t)t * KOUT + HID + (tid << 2)) = o;
}

// ---------------------------------------------------------------------------
extern "C" void kernel_launch(void* const* d_in, const int* in_sizes, int n_in,
                              void* d_out, int out_size, void* d_ws, size_t ws_size,
                              hipStream_t stream)
{
  const float* enc_input = (const float*)d_in[0];
  const float* hidden    = (const float*)d_in[1];
  const float* dec_input = (const float*)d_in[2];
  const float* enc_W_ih  = (const float*)d_in[3];
  const float* enc_W_hh  = (const float*)d_in[4];
  const float* enc_b_ih  = (const float*)d_in[5];
  const float* enc_b_hh  = (const float*)d_in[6];
  const float* dec_W_ih  = (const float*)d_in[7];
  const float* dec_W_hh  = (const float*)d_in[8];
  const float* dec_b_ih  = (const float*)d_in[9];
  const float* dec_b_hh  = (const float*)d_in[10];
  const float* attn_W    = (const float*)d_in[11];
  const float* attn_b    = (const float*)d_in[12];
  const float* out_W     = (const float*)d_in[13];
  const float* out_b     = (const float*)d_in[14];

  float* outs  = (float*)d_out;                         // [256, 32000]
  float* attns = (float*)d_out + (size_t)S_DEC * NCLS;  // [256, 512]

  // workspace layout (float units)
  float* wsf     = (float*)d_ws;
  float* xw_enc  = wsf + 0;                  // 524288
  float* xw_dec  = wsf + 524288;             // 262144
  float* Abuf    = wsf + 786432;             // 524288
  float* E       = wsf + 1310720;            // 524288
  float* wbuf    = wsf + 1835008;            // 131072
  unsigned int* hx_e = (unsigned int*)(wsf + 1966080);  // 2048 words
  unsigned int* hx_d = hx_e + 2048;                     // 2048 words
  f16*   HC16    = (f16*)(wsf + 1970176);    // 524288 halves
  float* P_enc   = wsf + 2232320;            // 8 * 524288 (aliased as P_A)
  float* P_dec   = wsf + 6426624;            // 8 * 262144
  float* P_A     = P_enc;

  init_hx<<<1, 1024, 0, stream>>>(hx_e);     // covers hx_e + hx_d (4096 words)

  gemm_nt_part<<<dim3(2, 16, 8), 256, 0, stream>>>(enc_input, enc_W_ih, P_enc,
                                                   S_ENC, HID, NCLS, 4000);
  gemm_nt_part<<<dim3(1, 16, 8), 256, 0, stream>>>(dec_input, dec_W_ih, P_dec,
                                                   S_DEC, HID, NCLS, 4000);
  reduce_bias<<<2048, 256, 0, stream>>>(P_enc, enc_b_ih, xw_enc, S_ENC * HID, 8);
  reduce_bias<<<1024, 256, 0, stream>>>(P_dec, dec_b_ih, xw_dec, S_DEC * HID, 8);

  rnn_scan<<<64, 256, 0, stream>>>(enc_W_hh, enc_b_hh, xw_enc, hidden,
                                   E, (f16*)nullptr, hx_e, S_ENC);

  gemm_nt_part<<<dim3(2, 16, 4), 256, 0, stream>>>(E, attn_W, P_A,
                                                   S_ENC, HID, HID, 256);
  reduce_bias<<<2048, 256, 0, stream>>>(P_A, attn_b, Abuf, S_ENC * HID, 4);

  rnn_scan<<<64, 256, 0, stream>>>(dec_W_hh, dec_b_hh, xw_dec, E + 511 * HID,
                                   (float*)nullptr, HC16, hx_d, S_DEC);

  attn_scores<<<256, 256, 0, stream>>>(HC16, Abuf, attns, wbuf);
  attn_context<<<256, 256, 0, stream>>>(wbuf, E, HC16);
  gemm_out_f16<<<500, 256, 0, stream>>>(HC16, out_W, out_b, outs);

  (void)in_sizes; (void)n_in; (void)out_size; (void)ws_size;
}